// Round 8
// baseline (121.206 us; speedup 1.0000x reference)
//
#include <hip/hip_runtime.h>

// YOLO decode, MI355X. R8: two-kernel split, pipelined conf kernel.
//  Conf kernel: block=(b,a,256-pos tile). 80 class planes staged via async
//  global_load_lds (16B/lane -> 1KB contiguous per wave-request) in 5
//  double-buffered 16-ch chunks (33KB LDS, 4 blocks/CU). Chunk k+1 loads
//  issued BEFORE chunk k compute (T14): read stream overlaps compute/store.
//  Conf stores: 4 back-to-back float4 = full 64B lines. Scores -> d_ws
//  contiguous (b,a,s), relocated by box kernel (fallback: direct scatter).
//  Box kernel: block=(b,80-s,all anchors); boxes/scores stores contiguous.

#define NCLS 80
#define NA   3
#define BB   32
#define WW   76
#define HH   76
#define WH   (WW*HH)          // 5776
#define PP   (WH*NA)          // 17328
#define TS   256
#define NTC  ((WH + TS - 1) / TS)   // 23 (last tile: 144 valid)
#define CCH  16
#define NCH  (NCLS / CCH)     // 5
#define STILE 80
#define NTB  ((WH + STILE - 1) / STILE)  // 73

__global__ __launch_bounds__(256, 4) void yolo_conf_kernel(
    const float* __restrict__ in,        // (B,255,W,H)
    float* __restrict__ conf,            // (B,P,80)
    float* __restrict__ scores,          // (B,P)       (fallback path)
    float* __restrict__ scores_ws,       // (B,3,WH)    (ws path)
    int use_ws)
{
    __shared__ float cbuf[2][CCH][TS];   // 32 KB
    __shared__ float obuf[TS];           // 1 KB

    const int t    = threadIdx.x;
    const int lane = t & 63;
    const int wv   = t >> 6;
    int bid  = blockIdx.x;
    int tile = bid % NTC;
    int ba   = bid / NTC;
    int a    = ba % NA;
    int b    = ba / NA;
    int s0   = tile * TS;
    int valid = WH - s0; if (valid > TS) valid = TS;   // 256 or 144 (mult of 4)

    const float* plane0 = in + ((size_t)b * 255 + a * 85) * WH;

    // per-lane 16B source offset within a plane row, clamped for the tail tile
    int off = 4 * lane;
    if (off > valid - 4) off = valid - 4;
    const int src = s0 + off;

    // ---- prologue: stage obj plane (wave 0) + chunk 0 (all waves) ----
    if (wv == 0) {
        __builtin_amdgcn_global_load_lds(
            (const __attribute__((address_space(1))) unsigned int*)(plane0 + (size_t)4 * WH + src),
            (__attribute__((address_space(3))) unsigned int*)&obuf[0], 16, 0, 0);
    }
    #pragma unroll
    for (int r = 0; r < 4; ++r) {
        int pl = wv * 4 + r;
        __builtin_amdgcn_global_load_lds(
            (const __attribute__((address_space(1))) unsigned int*)(plane0 + (size_t)(5 + pl) * WH + src),
            (__attribute__((address_space(3))) unsigned int*)&cbuf[0][0][0] + pl * TS, 16, 0, 0);
    }
    __syncthreads();

    float so = 1.0f / (1.0f + __expf(-obuf[t]));
    float rm = -1e30f;

    size_t cb = ((size_t)b * PP + (size_t)(s0 + t) * 3 + a) * NCLS;  // word offset
    const bool act = t < valid;

    for (int k = 0; k < NCH; ++k) {
        int cur = k & 1;
        if (k + 1 < NCH) {
            int nxt = cur ^ 1;
            #pragma unroll
            for (int r = 0; r < 4; ++r) {
                int pl = wv * 4 + r;
                __builtin_amdgcn_global_load_lds(
                    (const __attribute__((address_space(1))) unsigned int*)(plane0 + (size_t)(5 + (k + 1) * CCH + pl) * WH + src),
                    (__attribute__((address_space(3))) unsigned int*)&cbuf[nxt][0][0] + pl * TS, 16, 0, 0);
            }
        }

        // ---- compute 16 channels for position t (ds_reads are 2/bank = free) ----
        float4 o0, o1, o2, o3;
        {
            float v0, v1, v2, v3;
            v0 = cbuf[cur][ 0][t]; v1 = cbuf[cur][ 1][t]; v2 = cbuf[cur][ 2][t]; v3 = cbuf[cur][ 3][t];
            rm = fmaxf(rm, fmaxf(fmaxf(v0, v1), fmaxf(v2, v3)));
            o0.x = so / (1.0f + __expf(-v0)); o0.y = so / (1.0f + __expf(-v1));
            o0.z = so / (1.0f + __expf(-v2)); o0.w = so / (1.0f + __expf(-v3));
            v0 = cbuf[cur][ 4][t]; v1 = cbuf[cur][ 5][t]; v2 = cbuf[cur][ 6][t]; v3 = cbuf[cur][ 7][t];
            rm = fmaxf(rm, fmaxf(fmaxf(v0, v1), fmaxf(v2, v3)));
            o1.x = so / (1.0f + __expf(-v0)); o1.y = so / (1.0f + __expf(-v1));
            o1.z = so / (1.0f + __expf(-v2)); o1.w = so / (1.0f + __expf(-v3));
            v0 = cbuf[cur][ 8][t]; v1 = cbuf[cur][ 9][t]; v2 = cbuf[cur][10][t]; v3 = cbuf[cur][11][t];
            rm = fmaxf(rm, fmaxf(fmaxf(v0, v1), fmaxf(v2, v3)));
            o2.x = so / (1.0f + __expf(-v0)); o2.y = so / (1.0f + __expf(-v1));
            o2.z = so / (1.0f + __expf(-v2)); o2.w = so / (1.0f + __expf(-v3));
            v0 = cbuf[cur][12][t]; v1 = cbuf[cur][13][t]; v2 = cbuf[cur][14][t]; v3 = cbuf[cur][15][t];
            rm = fmaxf(rm, fmaxf(fmaxf(v0, v1), fmaxf(v2, v3)));
            o3.x = so / (1.0f + __expf(-v0)); o3.y = so / (1.0f + __expf(-v1));
            o3.z = so / (1.0f + __expf(-v2)); o3.w = so / (1.0f + __expf(-v3));
        }
        if (act) {
            float* cp = conf + cb + k * CCH;
            *reinterpret_cast<float4*>(cp +  0) = o0;
            *reinterpret_cast<float4*>(cp +  4) = o1;
            *reinterpret_cast<float4*>(cp +  8) = o2;
            *reinterpret_cast<float4*>(cp + 12) = o3;
        }
        __syncthreads();   // drains chunk k+1 gl_lds; protects cur buffer
    }

    float sc = so / (1.0f + __expf(-rm));
    if (act) {
        if (use_ws) scores_ws[((size_t)b * NA + a) * WH + s0 + t] = sc;
        else        scores[(size_t)b * PP + (size_t)(s0 + t) * 3 + a] = sc;
    }
}

__global__ __launch_bounds__(256, 4) void yolo_box_kernel(
    const float* __restrict__ in,
    const float* __restrict__ anchors,   // [d*3+a]
    float* __restrict__ boxes,           // (B,P,4)
    float* __restrict__ scores,          // (B,P)
    const float* __restrict__ scores_ws, // (B,3,WH)
    int use_ws)
{
    const int t   = threadIdx.x;
    int bid  = blockIdx.x;
    int tile = bid % NTB;
    int b    = bid / NTB;
    int s0   = tile * STILE;
    int vp   = (WH - s0) * 3; if (vp > STILE * 3) vp = STILE * 3;
    if (t >= vp) return;

    int p = s0 * 3 + t;
    int s = s0 + t / 3;
    int a = t % 3;

    const float* hp = in + ((size_t)b * 255 + a * 85) * WH + s;
    float tx = hp[0];
    float ty = hp[(size_t)1 * WH];
    float tw = hp[(size_t)2 * WH];
    float th = hp[(size_t)3 * WH];

    int w = s / HH, h = s - w * HH;
    float sx = 1.0f / (1.0f + __expf(-tx));
    float sy = 1.0f / (1.0f + __expf(-ty));
    float bx = (sx + (float)w) * (1.0f / WW);
    float by = (sy + (float)h) * (1.0f / HH);
    float bw = __expf(tw) * anchors[a];
    float bh = __expf(th) * anchors[3 + a];

    *reinterpret_cast<float4*>(boxes + ((size_t)b * PP + p) * 4) =
        make_float4(bx - 0.5f * bw, by - 0.5f * bh, bx + 0.5f * bw, by + 0.5f * bh);

    if (use_ws)
        scores[(size_t)b * PP + p] = scores_ws[((size_t)b * NA + a) * WH + s];
}

extern "C" void kernel_launch(void* const* d_in, const int* in_sizes, int n_in,
                              void* d_out, int out_size, void* d_ws, size_t ws_size,
                              hipStream_t stream) {
    const float* in      = (const float*)d_in[0];
    const float* anchors = (const float*)d_in[1];

    float* boxes  = (float*)d_out;                       // B*P*4
    float* conf   = boxes + (size_t)BB * PP * 4;         // B*P*80
    float* scores = conf + (size_t)BB * PP * NCLS;       // B*P

    const size_t ws_need = (size_t)BB * NA * WH * sizeof(float);  // 2,217,984 B
    int use_ws = ws_size >= ws_need ? 1 : 0;
    float* scores_ws = (float*)d_ws;

    yolo_conf_kernel<<<BB * NA * NTC, 256, 0, stream>>>(
        in, conf, scores, scores_ws, use_ws);
    yolo_box_kernel<<<BB * NTB, 256, 0, stream>>>(
        in, anchors, boxes, scores, scores_ws, use_ws);
}

// Round 10
// 77.884 us; speedup vs baseline: 1.5562x; 1.5562x over previous
//
#include <hip/hip_runtime.h>

// YOLO decode, MI355X. R9b = R7 structure (coalesced reads, LDS transpose,
// wave-contiguous output stores -- the proven 82-84us core) with:
//  - TS 64->32, PROW=260 kept: LDS 35KB -> 4 blocks/CU (R7: 66.5KB, 2/CU,
//    OccupancyPercent 19 -> phase-serialized blocks lacked overlap partners).
//  - ALL output stores nontemporal (via native ext_vector_type for the
//    builtin): 188MB of streaming output no longer evicts L3-resident input.
// Store law learned R1/R2/R5/R8: conf stores must be WAVE-contiguous
// (consecutive lanes -> consecutive 16B), which the q-linear mapping gives.

#define NCLS 80
#define NA   3
#define BB   32
#define WW   76
#define HH   76
#define WH   (WW*HH)          // 5776
#define PP   (WH*NA)          // 17328
#define TS   32               // positions per tile
#define NTILE ((WH + TS - 1) / TS)   // 181 (last tile: 16 valid)
#define PROW 260              // LDS row stride (words); 4 mod 32 -> bank rotate

typedef float f32x4 __attribute__((ext_vector_type(4)));

__global__ __launch_bounds__(256, 4) void yolo_decode_kernel(
    const float* __restrict__ in,       // (B, 255, W, H)
    const float* __restrict__ anchors,  // (2, 3) flat: [d*3 + a]
    float* __restrict__ boxes,          // (B, P, 4)
    float* __restrict__ conf,           // (B, P, 80)
    float* __restrict__ scores)         // (B, P)
{
    __shared__ float  cls[TS * PROW];     // [sl][a*80+c], 33280 B
    __shared__ float  so_buf[TS * NA];    // [p = sl*3+a], 384 B
    __shared__ float4 box_buf[TS * NA];   // [p], 1536 B

    const int t    = threadIdx.x;
    const int bid  = blockIdx.x;
    const int tile = bid % NTILE;
    const int b    = bid / NTILE;
    const int s0   = tile * TS;
    int valid = WH - s0; if (valid > TS) valid = TS;

    const float* bplane = in + (size_t)b * 255 * WH;

    // ---- head loads (t<96): 32-lane group per anchor, consecutive sl ----
    int a_h   = t >> 5;                 // 0..2
    int sl_h  = t & 31;
    int slc_h = sl_h < valid ? sl_h : valid - 1;
    float tx = 0.f, ty = 0.f, tw = 0.f, th = 0.f, to = 0.f;
    if (t < 96) {
        const float* hp = bplane + (size_t)(a_h * 85) * WH + s0 + slc_h;
        tx = hp[0];
        ty = hp[(size_t)1 * WH];
        tw = hp[(size_t)2 * WH];
        th = hp[(size_t)3 * WH];
        to = hp[(size_t)4 * WH];
    }

    // ---- stage 240 class channels transposed into LDS ----
    // unit = (ch-quad 0..59, sl 0..31); 1920 units, ~7.5/thread.
    // Loads: 32 consecutive sl of one plane per 32-lane group (128B, coalesced).
    // Write: one ds_write_b128 per unit into cls[sl][ch0..ch0+3].
    #pragma unroll 4
    for (int it = 0; it < 8; ++it) {
        int u = it * 256 + t;
        if (u < 60 * TS) {
            int qch = u >> 5;              // 0..59
            int sl  = u & 31;
            int slc = sl < valid ? sl : valid - 1;
            int ch0 = qch * 4;             // never straddles an anchor (80%4==0)
            int a   = ch0 / 80;
            int c0  = ch0 - a * 80;
            const float* gp = bplane + (size_t)(a * 85 + 5 + c0) * WH + s0 + slc;
            float v0 = gp[0];
            float v1 = gp[(size_t)1 * WH];
            float v2 = gp[(size_t)2 * WH];
            float v3 = gp[(size_t)3 * WH];
            *reinterpret_cast<float4*>(&cls[sl * PROW + ch0]) =
                make_float4(v0, v1, v2, v3);
        }
    }

    // ---- head compute -> LDS bufs (t<96) ----
    if (t < 96) {
        int s = s0 + slc_h;
        int w = s / HH;
        int h = s - w * HH;
        float sx = 1.0f / (1.0f + __expf(-tx));
        float sy = 1.0f / (1.0f + __expf(-ty));
        float bx = (sx + (float)w) * (1.0f / WW);
        float by = (sy + (float)h) * (1.0f / HH);
        float bw = __expf(tw) * anchors[a_h];
        float bh = __expf(th) * anchors[3 + a_h];
        int p = slc_h * 3 + a_h;           // clamped dups write identical data
        box_buf[p] = make_float4(bx - 0.5f * bw, by - 0.5f * bh,
                                 bx + 0.5f * bw, by + 0.5f * bh);
        so_buf[p] = 1.0f / (1.0f + __expf(-to));
    }

    __syncthreads();

    // ---- conf: 1920 quads, q-linear => wave-contiguous 16B stores ----
    size_t cbase = ((size_t)b * PP + (size_t)s0 * 3) * NCLS;   // word offset
    int vq = valid * 60;
    #pragma unroll 4
    for (int it = 0; it < 8; ++it) {
        int q = it * 256 + t;
        if (q < vq) {
            int p  = q / 20;
            int u  = q - p * 20;
            int sl = p / 3;
            int a  = p - sl * 3;
            float4 tv = *reinterpret_cast<const float4*>(&cls[sl * PROW + a * 80 + u * 4]);
            float so = so_buf[p];
            f32x4 o;
            o.x = so / (1.0f + __expf(-tv.x));
            o.y = so / (1.0f + __expf(-tv.y));
            o.z = so / (1.0f + __expf(-tv.z));
            o.w = so / (1.0f + __expf(-tv.w));
            __builtin_nontemporal_store(o,
                reinterpret_cast<f32x4*>(conf + cbase + (size_t)q * 4));
        }
    }

    // ---- boxes + scores (t<96), wave-contiguous stores ----
    if (t < 96) {
        int p = t;
        if (p < valid * 3) {
            float4 bq = box_buf[p];
            f32x4 bo = {bq.x, bq.y, bq.z, bq.w};
            __builtin_nontemporal_store(bo,
                reinterpret_cast<f32x4*>(boxes + ((size_t)b * PP + s0 * 3 + p) * 4));
        }
        int sl = p / 3;
        int a  = p - sl * 3;
        float mx = -1e30f;
        #pragma unroll
        for (int c4 = 0; c4 < 20; ++c4) {
            float4 v = *reinterpret_cast<const float4*>(&cls[sl * PROW + a * 80 + c4 * 4]);
            mx = fmaxf(mx, fmaxf(fmaxf(v.x, v.y), fmaxf(v.z, v.w)));
        }
        float sc = so_buf[p] * (1.0f / (1.0f + __expf(-mx)));
        if (p < valid * 3) {
            __builtin_nontemporal_store(sc, scores + (size_t)b * PP + s0 * 3 + p);
        }
    }
}

extern "C" void kernel_launch(void* const* d_in, const int* in_sizes, int n_in,
                              void* d_out, int out_size, void* d_ws, size_t ws_size,
                              hipStream_t stream) {
    const float* in      = (const float*)d_in[0];
    const float* anchors = (const float*)d_in[1];

    float* boxes  = (float*)d_out;                       // B*P*4
    float* conf   = boxes + (size_t)BB * PP * 4;         // B*P*80
    float* scores = conf + (size_t)BB * PP * NCLS;       // B*P

    int blocks = BB * NTILE;                             // 5792
    yolo_decode_kernel<<<blocks, 256, 0, stream>>>(in, anchors, boxes, conf, scores);
}